// Round 1
// baseline (372.266 us; speedup 1.0000x reference)
//
#include <hip/hip_runtime.h>
#include <stdint.h>

#define H_DIM 1024
#define I_DIM 4096
#define E_NUM 8
#define CAP   1024
#define NTOK  8192

typedef __attribute__((ext_vector_type(8))) short bf16x8;
typedef __attribute__((ext_vector_type(4))) float f32x4;

__device__ __forceinline__ unsigned short f2bf(float f){
  union { float f; uint32_t u; } v; v.f = f;
  uint32_t u = v.u;
  uint32_t r = (u + 0x7FFFu + ((u >> 16) & 1u)) >> 16;
  return (unsigned short)r;
}

// ---------------- zero output ----------------
__global__ void zero_kernel(float4* __restrict__ p, int n4){
  int i = blockIdx.x*blockDim.x + threadIdx.x;
  int stride = gridDim.x*blockDim.x;
  float4 z; z.x=0.f; z.y=0.f; z.z=0.f; z.w=0.f;
  for (; i < n4; i += stride) p[i] = z;
}

// ---------------- router softmax + x -> bf16 (first CAP tokens) ----------------
__global__ __launch_bounds__(256) void router_kernel(
    const float* __restrict__ x, const float* __restrict__ rw_w,
    const float* __restrict__ rb, unsigned short* __restrict__ xb,
    float* __restrict__ rwout)
{
  int c = blockIdx.x;
  int t = threadIdx.x;
  float acc[E_NUM];
  #pragma unroll
  for (int e=0;e<E_NUM;e++) acc[e]=0.f;
  const float* xr = x + (size_t)c*H_DIM;
  for (int h=t; h<H_DIM; h+=256){
    float xv = xr[h];
    xb[(size_t)c*H_DIM + h] = f2bf(xv);
    #pragma unroll
    for (int e=0;e<E_NUM;e++) acc[e] += xv * rw_w[e*H_DIM + h];
  }
  __shared__ float part[256][E_NUM];
  #pragma unroll
  for (int e=0;e<E_NUM;e++) part[t][e]=acc[e];
  __syncthreads();
  for (int s=128; s>0; s>>=1){
    if (t<s){
      #pragma unroll
      for (int e=0;e<E_NUM;e++) part[t][e]+=part[t+s][e];
    }
    __syncthreads();
  }
  if (t==0){
    float l[E_NUM], mx=-1e30f;
    #pragma unroll
    for (int e=0;e<E_NUM;e++){ l[e]=part[0][e]+rb[e]; mx=fmaxf(mx,l[e]); }
    float s=0.f;
    #pragma unroll
    for (int e=0;e<E_NUM;e++){ l[e]=expf(l[e]-mx); s+=l[e]; }
    float inv = 1.f/s;
    #pragma unroll
    for (int e=0;e<E_NUM;e++) rwout[c*E_NUM+e] = l[e]*inv;
  }
}

// ---------------- fp32 -> bf16 transpose (src RxC -> dst CxR) ----------------
__global__ __launch_bounds__(256) void transpose_cvt(
    const float* __restrict__ src, unsigned short* __restrict__ dst,
    int R, int C, long srcZ, long dstZ)
{
  src += (size_t)blockIdx.z * srcZ;
  dst += (size_t)blockIdx.z * dstZ;
  __shared__ float tile[32][33];
  int c0 = blockIdx.x*32, r0 = blockIdx.y*32;
  int tx = threadIdx.x, ty = threadIdx.y;
  #pragma unroll
  for (int j=ty; j<32; j+=8)
    tile[j][tx] = src[(size_t)(r0+j)*C + c0+tx];
  __syncthreads();
  #pragma unroll
  for (int j=ty; j<32; j+=8)
    dst[(size_t)(c0+j)*R + r0+tx] = f2bf(tile[tx][j]);
}

// ---------------- bf16 GEMM, B transposed (N x K), 128x128 tile, BK=32 ----------------
// MODE 0: inter epilogue  out = bf16( relu(acc) * rw[row,e] )   (row-stride E*I, col off e*I)
// MODE 1: atomicAdd fp32 into outAdd (row-stride H)
template<int MODE>
__global__ __launch_bounds__(256) void gemm_bt(
    const unsigned short* __restrict__ A, int lda, long eStrideA,
    const unsigned short* __restrict__ B, int ldb, long eStrideB,
    int K,
    const float* __restrict__ rw,
    unsigned short* __restrict__ outInter,
    float* __restrict__ outAdd)
{
  __shared__ unsigned short As[128*32];
  __shared__ unsigned short Bs[128*32];
  int m0 = blockIdx.x*128;
  int n0 = blockIdx.y*128;
  int e  = blockIdx.z;
  const unsigned short* Ab = A + (size_t)m0*lda + (size_t)e*eStrideA;
  const unsigned short* Bb = B + (size_t)n0*ldb + (size_t)e*eStrideB;

  int tid  = threadIdx.x;
  int wv   = tid>>6, lane = tid&63;
  int wr   = wv>>1,  wc   = wv&1;
  int lrow = lane&15;
  int lk   = (lane>>4)*8;

  f32x4 acc[4][4];
  #pragma unroll
  for (int i=0;i<4;i++)
    #pragma unroll
    for (int j=0;j<4;j++)
      acc[i][j] = (f32x4){0.f,0.f,0.f,0.f};

  for (int kt=0; kt<K; kt+=32){
    #pragma unroll
    for (int i=0;i<2;i++){
      int be  = (wv*2+i)*512;          // wave-uniform LDS base (elements)
      int idx = be + lane*8;           // per-lane element index in tile
      int r   = idx>>5, kk = idx&31;
      __builtin_amdgcn_global_load_lds(
        (const __attribute__((address_space(1))) void*)(Ab + (size_t)r*lda + kt + kk),
        (__attribute__((address_space(3))) void*)(&As[be]), 16, 0, 0);
      __builtin_amdgcn_global_load_lds(
        (const __attribute__((address_space(1))) void*)(Bb + (size_t)r*ldb + kt + kk),
        (__attribute__((address_space(3))) void*)(&Bs[be]), 16, 0, 0);
    }
    __syncthreads();   // drains vmcnt before barrier -> LDS tile ready

    bf16x8 af[4], bfr[4];
    #pragma unroll
    for (int f=0;f<4;f++)
      af[f]  = *(const bf16x8*)&As[(wr*64 + f*16 + lrow)*32 + lk];
    #pragma unroll
    for (int f=0;f<4;f++)
      bfr[f] = *(const bf16x8*)&Bs[(wc*64 + f*16 + lrow)*32 + lk];

    #pragma unroll
    for (int fm=0;fm<4;fm++)
      #pragma unroll
      for (int fn=0;fn<4;fn++)
        acc[fm][fn] = __builtin_amdgcn_mfma_f32_16x16x32_bf16(af[fm], bfr[fn], acc[fm][fn], 0, 0, 0);

    __syncthreads();   // protect LDS before next stage overwrites
  }

  // epilogue: C/D layout col = lane&15, row = (lane>>4)*4 + reg
  #pragma unroll
  for (int fm=0;fm<4;fm++){
    #pragma unroll
    for (int fn=0;fn<4;fn++){
      #pragma unroll
      for (int r=0;r<4;r++){
        int m  = wr*64 + fm*16 + (lane>>4)*4 + r;
        int n  = wc*64 + fn*16 + (lane&15);
        int gm = m0 + m;
        int gn = n0 + n;
        float v = acc[fm][fn][r];
        if (MODE==0){
          v = fmaxf(v, 0.f) * rw[gm*E_NUM + e];
          outInter[(size_t)gm*(E_NUM*I_DIM) + (size_t)e*I_DIM + gn] = f2bf(v);
        } else {
          atomicAdd(&outAdd[(size_t)gm*H_DIM + gn], v);
        }
      }
    }
  }
}

extern "C" void kernel_launch(void* const* d_in, const int* in_sizes, int n_in,
                              void* d_out, int out_size, void* d_ws, size_t ws_size,
                              hipStream_t stream)
{
  const float* x   = (const float*)d_in[0];
  const float* rww = (const float*)d_in[1];
  const float* rwb = (const float*)d_in[2];
  const float* w1  = (const float*)d_in[3];  // (E, H, I)
  const float* w2  = (const float*)d_in[4];  // (E, I, H)
  float* out = (float*)d_out;

  char* ws = (char*)d_ws;
  float*          rwout = (float*)(ws);                         // 32 KB
  unsigned short* xb    = (unsigned short*)(ws + (1u<<16));     // 2 MB  @64KB
  unsigned short* inter = (unsigned short*)(ws + (4ull<<20));   // 64 MB @4MB
  unsigned short* wt    = (unsigned short*)(ws + (68ull<<20));  // 64 MB @68MB
  const size_t needed = 132ull<<20;

  // output rows >= CAP are exactly zero; rows < CAP accumulated via atomics
  zero_kernel<<<2048, 256, 0, stream>>>((float4*)out, out_size/4);

  if (ws_size < needed) return;  // signature: output stays exactly zero

  router_kernel<<<CAP, 256, 0, stream>>>(x, rww, rwb, xb, rwout);

  dim3 tb(32,8);
  // W1 (E,H,I) -> W1^T per expert (I x H) bf16
  transpose_cvt<<<dim3(I_DIM/32, H_DIM/32, E_NUM), tb, 0, stream>>>(
      w1, wt, H_DIM, I_DIM, (long)H_DIM*I_DIM, (long)I_DIM*H_DIM);

  // GEMM1: inter[c, e*I+n] = bf16( relu( xb[c,:] @ W1_e[:,n] ) * rw[c,e] )
  gemm_bt<0><<<dim3(CAP/128, I_DIM/128, E_NUM), 256, 0, stream>>>(
      xb, H_DIM, 0L,
      wt, H_DIM, (long)I_DIM*H_DIM,
      H_DIM, rwout, inter, nullptr);

  // W2 flat (E*I x H) -> W2^T (H x E*I) bf16
  transpose_cvt<<<dim3(H_DIM/32, (E_NUM*I_DIM)/32, 1), tb, 0, stream>>>(
      w2, wt, E_NUM*I_DIM, H_DIM, 0L, 0L);

  // GEMM2 (split-K over experts): out[c,h] += inter[c, e*I:] @ W2^T[h, e*I:]
  gemm_bt<1><<<dim3(CAP/128, H_DIM/128, E_NUM), 256, 0, stream>>>(
      inter, E_NUM*I_DIM, 4096L,
      wt,    E_NUM*I_DIM, 4096L,
      I_DIM, nullptr, nullptr, out);
}

// Round 2
// 321.529 us; speedup vs baseline: 1.1578x; 1.1578x over previous
//
#include <hip/hip_runtime.h>
#include <stdint.h>

#define H_DIM 1024
#define I_DIM 4096
#define E_NUM 8
#define CAP   1024

typedef __attribute__((ext_vector_type(8))) short bf16x8;
typedef __attribute__((ext_vector_type(4))) float f32x4;

__device__ __forceinline__ unsigned short f2bf(float f){
  union { float f; uint32_t u; } v; v.f = f;
  uint32_t u = v.u;
  uint32_t r = (u + 0x7FFFu + ((u >> 16) & 1u)) >> 16;
  return (unsigned short)r;
}

// ---------------- zero output ----------------
__global__ void zero_kernel(float4* __restrict__ p, int n4){
  int i = blockIdx.x*blockDim.x + threadIdx.x;
  int stride = gridDim.x*blockDim.x;
  float4 z; z.x=0.f; z.y=0.f; z.z=0.f; z.w=0.f;
  for (; i < n4; i += stride) p[i] = z;
}

// ---------------- router softmax + x -> bf16 (first CAP tokens) ----------------
__global__ __launch_bounds__(256) void router_kernel(
    const float* __restrict__ x, const float* __restrict__ rw_w,
    const float* __restrict__ rb, unsigned short* __restrict__ xb,
    float* __restrict__ rwout)
{
  int c = blockIdx.x;
  int t = threadIdx.x;
  float acc[E_NUM];
  #pragma unroll
  for (int e=0;e<E_NUM;e++) acc[e]=0.f;
  const float* xr = x + (size_t)c*H_DIM;
  for (int h=t; h<H_DIM; h+=256){
    float xv = xr[h];
    xb[(size_t)c*H_DIM + h] = f2bf(xv);
    #pragma unroll
    for (int e=0;e<E_NUM;e++) acc[e] += xv * rw_w[e*H_DIM + h];
  }
  __shared__ float part[256][E_NUM];
  #pragma unroll
  for (int e=0;e<E_NUM;e++) part[t][e]=acc[e];
  __syncthreads();
  for (int s=128; s>0; s>>=1){
    if (t<s){
      #pragma unroll
      for (int e=0;e<E_NUM;e++) part[t][e]+=part[t+s][e];
    }
    __syncthreads();
  }
  if (t==0){
    float l[E_NUM], mx=-1e30f;
    #pragma unroll
    for (int e=0;e<E_NUM;e++){ l[e]=part[0][e]+rb[e]; mx=fmaxf(mx,l[e]); }
    float s=0.f;
    #pragma unroll
    for (int e=0;e<E_NUM;e++){ l[e]=expf(l[e]-mx); s+=l[e]; }
    float inv = 1.f/s;
    #pragma unroll
    for (int e=0;e<E_NUM;e++) rwout[c*E_NUM+e] = l[e]*inv;
  }
}

// ---------------- fp32 -> bf16 transpose (src RxC -> dst CxR) ----------------
__global__ __launch_bounds__(256) void transpose_cvt(
    const float* __restrict__ src, unsigned short* __restrict__ dst,
    int R, int C, long srcZ, long dstZ)
{
  src += (size_t)blockIdx.z * srcZ;
  dst += (size_t)blockIdx.z * dstZ;
  __shared__ float tile[32][33];
  int c0 = blockIdx.x*32, r0 = blockIdx.y*32;
  int tx = threadIdx.x, ty = threadIdx.y;
  #pragma unroll
  for (int j=ty; j<32; j+=8)
    tile[j][tx] = src[(size_t)(r0+j)*C + c0+tx];
  __syncthreads();
  #pragma unroll
  for (int j=ty; j<32; j+=8)
    dst[(size_t)(c0+j)*R + r0+tx] = f2bf(tile[tx][j]);
}

// ---------------- 256x256 8-phase bf16 GEMM, B transposed (N-major) ----------------
// 8 waves (2M x 4N), BK=64, double-buffered 128KB LDS, T2 XOR swizzle,
// global_load_lds linear-dest + pre-swizzled global source, T5 setprio,
// T1 XCD-aware block swizzle. MODE 0: relu*rw -> bf16 inter. MODE 1: atomicAdd fp32.
template<int MODE>
__global__ __launch_bounds__(512, 2) void gemm8p(
    const unsigned short* __restrict__ A, int lda, long aZ,
    const unsigned short* __restrict__ B, int ldb, long bZ,
    int NT, int tilesPerZ,
    const float* __restrict__ rw,
    unsigned short* __restrict__ outInter,
    float* __restrict__ outAdd)
{
  extern __shared__ char smem[];   // 131072 bytes: [2 dbuf][A 32KB | B 32KB]

  // T1: XCD-aware swizzle (gridDim.x % 8 == 0 in all our launches)
  int nwg = gridDim.x;
  int id  = blockIdx.x;
  int swz = (id & 7)*(nwg >> 3) + (id >> 3);
  int z   = swz / tilesPerZ;
  int rr_ = swz - z*tilesPerZ;
  int mt  = rr_ & 3, nt = rr_ >> 2;
  int m0  = mt*256, n0 = nt*256;

  const unsigned short* Ab = A + (size_t)z*aZ + (size_t)m0*lda;
  const unsigned short* Bb = B + (size_t)z*bZ + (size_t)n0*ldb;

  int tid  = threadIdx.x;
  int w    = tid >> 6, l = tid & 63;
  int wr   = w >> 2,  wc = w & 3;       // wave grid 2M x 4N
  int lrow = l & 15,  lq = l >> 4;
  int r7   = lrow & 7;

  // staging constants: thread covers 16B at linear LDS slot; global source
  // column is inverse-swizzled so a plain XOR on the read side round-trips.
  int srow0 = (w*2+0)*8 + (l>>3);       // row within 128-row half, load 0
  int srow1 = (w*2+1)*8 + (l>>3);       // row within 128-row half, load 1
  int sswz  = ((l&7) ^ ((l>>3)&7)) * 8; // element offset inside 64-elem K-chunk
  int ldsS0 = w*2048;
  int ldsS1 = w*2048 + 1024;

  auto stage = [&](int q, int sbase, int kt){
    const unsigned short* src; int ldx, rowb, ldsb;
    if (q < 2){ src = Ab; ldx = lda; rowb = q*128;     ldsb = sbase + q*16384; }
    else      { src = Bb; ldx = ldb; rowb = (q-2)*128; ldsb = sbase + 32768 + (q-2)*16384; }
    __builtin_amdgcn_global_load_lds(
      (const __attribute__((address_space(1))) void*)(src + (size_t)(rowb+srow0)*ldx + kt + sswz),
      (__attribute__((address_space(3))) void*)(smem + ldsb + ldsS0), 16, 0, 0);
    __builtin_amdgcn_global_load_lds(
      (const __attribute__((address_space(1))) void*)(src + (size_t)(rowb+srow1)*ldx + kt + sswz),
      (__attribute__((address_space(3))) void*)(smem + ldsb + ldsS1), 16, 0, 0);
  };

  f32x4 acc[8][4];
  #pragma unroll
  for (int i=0;i<8;i++)
    #pragma unroll
    for (int j=0;j<4;j++)
      acc[i][j] = (f32x4){0.f,0.f,0.f,0.f};

  // prologue: stage K-tile 0 into buffer 0
  #pragma unroll
  for (int q=0;q<4;q++) stage(q, 0, 0);

  for (int t=0; t<NT; t++){
    int dbase = (t&1) << 16;
    int sbase = dbase ^ 65536;
    int kt1   = (t+1)*64;
    bool pf   = (t+1 < NT);

    // K-tile boundary: own stages landed, then all waves' stages landed.
    asm volatile("s_waitcnt vmcnt(0)" ::: "memory");
    __builtin_amdgcn_s_barrier();
    __builtin_amdgcn_sched_barrier(0);

    #pragma unroll
    for (int q=0;q<4;q++){
      bf16x8 af[4][2], bfr[2][2];
      #pragma unroll
      for (int m=0;m<4;m++){
        int Mf  = (q>>1)*4 + m;
        int row = wr*128 + Mf*16 + lrow;
        #pragma unroll
        for (int kk=0;kk<2;kk++){
          int off = dbase + row*128 + (((kk*4+lq) ^ r7) << 4);
          af[m][kk] = *(const bf16x8*)(smem + off);
        }
      }
      #pragma unroll
      for (int n=0;n<2;n++){
        int Nf  = (q&1)*2 + n;
        int row = wc*64 + Nf*16 + lrow;
        #pragma unroll
        for (int kk=0;kk<2;kk++){
          int off = dbase + 32768 + row*128 + (((kk*4+lq) ^ r7) << 4);
          bfr[n][kk] = *(const bf16x8*)(smem + off);
        }
      }
      // issue next-tile prefetch early (phases 0,1: two halves each) so the
      // boundary vmcnt(0) finds them ~2.5 phases (~1500 cyc) old.
      if (pf && q < 2){ stage(q*2, sbase, kt1); stage(q*2+1, sbase, kt1); }

      __builtin_amdgcn_s_barrier();
      __builtin_amdgcn_s_setprio(1);
      #pragma unroll
      for (int kk=0;kk<2;kk++)
        #pragma unroll
        for (int m=0;m<4;m++)
          #pragma unroll
          for (int n=0;n<2;n++){
            int Mf=(q>>1)*4+m, Nf=(q&1)*2+n;
            acc[Mf][Nf] = __builtin_amdgcn_mfma_f32_16x16x32_bf16(af[m][kk], bfr[n][kk], acc[Mf][Nf], 0, 0, 0);
          }
      __builtin_amdgcn_s_setprio(0);
      __builtin_amdgcn_s_barrier();
    }
  }

  // epilogue: C/D layout col = lane&15, row = (lane>>4)*4 + reg
  #pragma unroll
  for (int Mf=0;Mf<8;Mf++){
    #pragma unroll
    for (int Nf=0;Nf<4;Nf++){
      #pragma unroll
      for (int rg=0;rg<4;rg++){
        int gm = m0 + wr*128 + Mf*16 + lq*4 + rg;
        int gn = n0 + wc*64 + Nf*16 + lrow;
        float v = acc[Mf][Nf][rg];
        if (MODE==0){
          v = fmaxf(v, 0.f) * rw[gm*E_NUM + z];
          outInter[(size_t)gm*(E_NUM*I_DIM) + (size_t)z*I_DIM + gn] = f2bf(v);
        } else {
          atomicAdd(&outAdd[(size_t)gm*H_DIM + gn], v);
        }
      }
    }
  }
}

extern "C" void kernel_launch(void* const* d_in, const int* in_sizes, int n_in,
                              void* d_out, int out_size, void* d_ws, size_t ws_size,
                              hipStream_t stream)
{
  const float* x   = (const float*)d_in[0];
  const float* rww = (const float*)d_in[1];
  const float* rwb = (const float*)d_in[2];
  const float* w1  = (const float*)d_in[3];  // (E, H, I)
  const float* w2  = (const float*)d_in[4];  // (E, I, H)
  float* out = (float*)d_out;

  char* ws = (char*)d_ws;
  float*          rwout = (float*)(ws);                         // 32 KB
  unsigned short* xb    = (unsigned short*)(ws + (1u<<16));     // 2 MB  @64KB
  unsigned short* inter = (unsigned short*)(ws + (4ull<<20));   // 64 MB @4MB
  unsigned short* wt    = (unsigned short*)(ws + (68ull<<20));  // 64 MB @68MB
  const size_t needed = 132ull<<20;

  zero_kernel<<<2048, 256, 0, stream>>>((float4*)out, out_size/4);
  if (ws_size < needed) return;

  void* k0 = (void*)gemm8p<0>;
  void* k1 = (void*)gemm8p<1>;
  hipFuncSetAttribute(k0, hipFuncAttributeMaxDynamicSharedMemorySize, 131072);
  hipFuncSetAttribute(k1, hipFuncAttributeMaxDynamicSharedMemorySize, 131072);

  router_kernel<<<CAP, 256, 0, stream>>>(x, rww, rwb, xb, rwout);

  dim3 tb(32,8);
  // W1 (E,H,I) -> W1^T per expert (I x H) bf16
  transpose_cvt<<<dim3(I_DIM/32, H_DIM/32, E_NUM), tb, 0, stream>>>(
      w1, wt, H_DIM, I_DIM, (long)H_DIM*I_DIM, (long)I_DIM*H_DIM);

  // GEMM1: inter[c, e*I+n] = bf16( relu( xb @ W1_e^T ) * rw[c,e] )
  // grid 512 = 4 mtiles x 16 ntiles x 8 experts
  gemm8p<0><<<512, 512, 131072, stream>>>(
      xb, H_DIM, 0L,
      wt, H_DIM, (long)I_DIM*H_DIM,
      H_DIM/64, 64, rwout, inter, nullptr);

  // W2 flat (E*I x H) -> W2^T (H x E*I) bf16
  transpose_cvt<<<dim3(H_DIM/32, (E_NUM*I_DIM)/32, 1), tb, 0, stream>>>(
      w2, wt, E_NUM*I_DIM, H_DIM, 0L, 0L);

  // GEMM2: out[c,h] += inter[c,:] @ W2^T[h,:], split-K: z = e*2+kh (16 slices of 2048)
  // grid 256 = 4 mtiles x 4 ntiles x 16 z
  gemm8p<1><<<256, 512, 131072, stream>>>(
      inter, E_NUM*I_DIM, 2048L,
      wt,    E_NUM*I_DIM, 2048L,
      2048/64, 16, nullptr, nullptr, out);
}

// Round 3
// 307.148 us; speedup vs baseline: 1.2120x; 1.0468x over previous
//
#include <hip/hip_runtime.h>
#include <stdint.h>

#define H_DIM 1024
#define I_DIM 4096
#define E_NUM 8
#define CAP   1024

typedef __attribute__((ext_vector_type(8))) short bf16x8;
typedef __attribute__((ext_vector_type(4))) float f32x4;

#define AS1 __attribute__((address_space(1)))
#define AS3 __attribute__((address_space(3)))

__device__ __forceinline__ unsigned short f2bf(float f){
  union { float f; uint32_t u; } v; v.f = f;
  uint32_t u = v.u;
  uint32_t r = (u + 0x7FFFu + ((u >> 16) & 1u)) >> 16;
  return (unsigned short)r;
}

// ---------------- zero output ----------------
__global__ void zero_kernel(float4* __restrict__ p, int n4){
  int i = blockIdx.x*blockDim.x + threadIdx.x;
  int stride = gridDim.x*blockDim.x;
  float4 z; z.x=0.f; z.y=0.f; z.z=0.f; z.w=0.f;
  for (; i < n4; i += stride) p[i] = z;
}

// ---------------- router softmax + x -> bf16 (first CAP tokens) ----------------
__global__ __launch_bounds__(256) void router_kernel(
    const float* __restrict__ x, const float* __restrict__ rw_w,
    const float* __restrict__ rb, unsigned short* __restrict__ xb,
    float* __restrict__ rwout)
{
  int c = blockIdx.x;
  int t = threadIdx.x;
  float acc[E_NUM];
  #pragma unroll
  for (int e=0;e<E_NUM;e++) acc[e]=0.f;
  const float* xr = x + (size_t)c*H_DIM;
  for (int h=t; h<H_DIM; h+=256){
    float xv = xr[h];
    xb[(size_t)c*H_DIM + h] = f2bf(xv);
    #pragma unroll
    for (int e=0;e<E_NUM;e++) acc[e] += xv * rw_w[e*H_DIM + h];
  }
  __shared__ float part[256][E_NUM];
  #pragma unroll
  for (int e=0;e<E_NUM;e++) part[t][e]=acc[e];
  __syncthreads();
  for (int s=128; s>0; s>>=1){
    if (t<s){
      #pragma unroll
      for (int e=0;e<E_NUM;e++) part[t][e]+=part[t+s][e];
    }
    __syncthreads();
  }
  if (t==0){
    float l[E_NUM], mx=-1e30f;
    #pragma unroll
    for (int e=0;e<E_NUM;e++){ l[e]=part[0][e]+rb[e]; mx=fmaxf(mx,l[e]); }
    float s=0.f;
    #pragma unroll
    for (int e=0;e<E_NUM;e++){ l[e]=expf(l[e]-mx); s+=l[e]; }
    float inv = 1.f/s;
    #pragma unroll
    for (int e=0;e<E_NUM;e++) rwout[c*E_NUM+e] = l[e]*inv;
  }
}

// ---------------- fp32 -> bf16 transpose (src RxC -> dst CxR) ----------------
__global__ __launch_bounds__(256) void transpose_cvt(
    const float* __restrict__ src, unsigned short* __restrict__ dst,
    int R, int C, long srcZ, long dstZ)
{
  src += (size_t)blockIdx.z * srcZ;
  dst += (size_t)blockIdx.z * dstZ;
  __shared__ float tile[32][33];
  int c0 = blockIdx.x*32, r0 = blockIdx.y*32;
  int tx = threadIdx.x, ty = threadIdx.y;
  #pragma unroll
  for (int j=ty; j<32; j+=8)
    tile[j][tx] = src[(size_t)(r0+j)*C + c0+tx];
  __syncthreads();
  #pragma unroll
  for (int j=ty; j<32; j+=8)
    dst[(size_t)(c0+j)*R + r0+tx] = f2bf(tile[tx][j]);
}

// ---- 256x256 bf16 GEMM, B N-major; counted-vmcnt half-K-tile pipeline ----
// 4 LDS buffers x 32KB (A[256x32]+B[256x32]), depth-3 prefetch, vmcnt(8) at
// each half boundary (never 0 in steady state), 1 barrier per half, 32 MFMA
// per half per wave under setprio. Every wave stages 4 gloads per half so the
// per-wave vmcnt + barrier proves buffer readiness for all waves.
// MODE 0: relu*rw -> bf16 inter.  MODE 1: atomicAdd fp32.
template<int MODE>
__global__ __launch_bounds__(512, 2) void gemm4b(
    const unsigned short* __restrict__ A, int lda, long aZ,
    const unsigned short* __restrict__ B, int ldb, long bZ,
    int NH, int tilesPerZ,
    const float* __restrict__ rw,
    unsigned short* __restrict__ outInter,
    float* __restrict__ outAdd)
{
  extern __shared__ char smem[];   // 131072 = 4 bufs x (A 16KB | B 16KB)

  // T1: XCD-aware swizzle (gridDim.x % 8 == 0)
  int nwg = gridDim.x;
  int id  = blockIdx.x;
  int swz = (id & 7)*(nwg >> 3) + (id >> 3);
  int z   = swz / tilesPerZ;
  int rr_ = swz - z*tilesPerZ;
  int mt  = rr_ & 3, nt = rr_ >> 2;
  int m0  = mt*256, n0 = nt*256;

  const unsigned short* Ab = A + (size_t)z*aZ + (size_t)m0*lda;
  const unsigned short* Bb = B + (size_t)z*bZ + (size_t)n0*ldb;

  int tid  = threadIdx.x;
  int w    = tid >> 6, l = tid & 63;
  int wr   = w >> 2,  wc = w & 3;       // wave grid 2M x 4N
  int lrow = l & 15,  lq = l >> 4;

  // read-side swizzle: slot = lq ^ ((row>>1)&3); row%16==lrow and frag bases
  // are multiples of 16, so the XOR term is a per-lane constant.
  int rsw = (lq ^ ((lrow>>1)&3)) << 4;          // byte offset of 16B slot

  // staging: wave w covers rows [w*32, w*32+32) of both A and B halves.
  // lane l -> row r = w*32 + c2*16 + (l>>3... (l>>2), slot j = l&3.
  // source slot s = j ^ ((r>>1)&3) = (l&3) ^ ((l>>3)&3)  (involution).
  int srow  = (l >> 2);
  int sslot = ((l & 3) ^ ((l >> 3) & 3)) * 8;   // element offset in 32-elem row
  size_t aOff0 = (size_t)(w*32 + srow)      * lda + sslot;
  size_t aOff1 = (size_t)(w*32 + 16 + srow) * lda + sslot;
  size_t bOff0 = (size_t)(w*32 + srow)      * ldb + sslot;
  size_t bOff1 = (size_t)(w*32 + 16 + srow) * ldb + sslot;
  int ldsA0 = (w*32)*64, ldsA1 = (w*32+16)*64;

  auto stageHalf = [&](int h){
    char* lb = smem + ((h & 3) << 15);
    int kb = h << 5;
    __builtin_amdgcn_global_load_lds((const AS1 void*)(Ab + aOff0 + kb),
        (AS3 void*)(lb + ldsA0), 16, 0, 0);
    __builtin_amdgcn_global_load_lds((const AS1 void*)(Ab + aOff1 + kb),
        (AS3 void*)(lb + ldsA1), 16, 0, 0);
    __builtin_amdgcn_global_load_lds((const AS1 void*)(Bb + bOff0 + kb),
        (AS3 void*)(lb + 16384 + ldsA0), 16, 0, 0);
    __builtin_amdgcn_global_load_lds((const AS1 void*)(Bb + bOff1 + kb),
        (AS3 void*)(lb + 16384 + ldsA1), 16, 0, 0);
  };

  f32x4 acc[8][4];
  #pragma unroll
  for (int i=0;i<8;i++)
    #pragma unroll
    for (int j=0;j<4;j++)
      acc[i][j] = (f32x4){0.f,0.f,0.f,0.f};

  auto compute = [&](int h){
    char* lb = smem + ((h & 3) << 15);
    bf16x8 af[8], bfr[4];
    #pragma unroll
    for (int Mf=0;Mf<8;Mf++)
      af[Mf] = *(const bf16x8*)(lb + (wr*128 + Mf*16 + lrow)*64 + rsw);
    #pragma unroll
    for (int Nf=0;Nf<4;Nf++)
      bfr[Nf] = *(const bf16x8*)(lb + 16384 + (wc*64 + Nf*16 + lrow)*64 + rsw);
    __builtin_amdgcn_s_setprio(1);
    #pragma unroll
    for (int Mf=0;Mf<8;Mf++)
      #pragma unroll
      for (int Nf=0;Nf<4;Nf++)
        acc[Mf][Nf] = __builtin_amdgcn_mfma_f32_16x16x32_bf16(af[Mf], bfr[Nf], acc[Mf][Nf], 0, 0, 0);
    __builtin_amdgcn_s_setprio(0);
  };

  // prologue: depth-3 prefetch
  stageHalf(0); stageHalf(1); stageHalf(2);

  // steady state: wait own vmcnt(8) (halves h+1,h+2 in flight), barrier, then
  // stage h+3 into the buffer all waves finished reading at half h-1.
  int h = 0;
  for (; h < NH-2; ++h){
    asm volatile("s_waitcnt vmcnt(8)" ::: "memory");
    __builtin_amdgcn_s_barrier();
    if (h+3 < NH) stageHalf(h+3);
    compute(h);
  }
  asm volatile("s_waitcnt vmcnt(4)" ::: "memory");
  __builtin_amdgcn_s_barrier();
  compute(NH-2);
  asm volatile("s_waitcnt vmcnt(0)" ::: "memory");
  __builtin_amdgcn_s_barrier();
  compute(NH-1);

  // epilogue: C/D layout col = lane&15, row = (lane>>4)*4 + reg
  #pragma unroll
  for (int Mf=0;Mf<8;Mf++){
    #pragma unroll
    for (int Nf=0;Nf<4;Nf++){
      #pragma unroll
      for (int rg=0;rg<4;rg++){
        int gm = m0 + wr*128 + Mf*16 + lq*4 + rg;
        int gn = n0 + wc*64 + Nf*16 + lrow;
        float v = acc[Mf][Nf][rg];
        if (MODE==0){
          v = fmaxf(v, 0.f) * rw[gm*E_NUM + z];
          outInter[(size_t)gm*(E_NUM*I_DIM) + (size_t)z*I_DIM + gn] = f2bf(v);
        } else {
          atomicAdd(&outAdd[(size_t)gm*H_DIM + gn], v);
        }
      }
    }
  }
}

extern "C" void kernel_launch(void* const* d_in, const int* in_sizes, int n_in,
                              void* d_out, int out_size, void* d_ws, size_t ws_size,
                              hipStream_t stream)
{
  const float* x   = (const float*)d_in[0];
  const float* rww = (const float*)d_in[1];
  const float* rwb = (const float*)d_in[2];
  const float* w1  = (const float*)d_in[3];  // (E, H, I)
  const float* w2  = (const float*)d_in[4];  // (E, I, H)
  float* out = (float*)d_out;

  char* ws = (char*)d_ws;
  float*          rwout = (float*)(ws);                         // 32 KB
  unsigned short* xb    = (unsigned short*)(ws + (1u<<16));     // 2 MB  @64KB
  unsigned short* inter = (unsigned short*)(ws + (4ull<<20));   // 64 MB @4MB
  unsigned short* wt    = (unsigned short*)(ws + (68ull<<20));  // 64 MB @68MB
  const size_t needed = 132ull<<20;

  zero_kernel<<<2048, 256, 0, stream>>>((float4*)out, out_size/4);
  if (ws_size < needed) return;

  void* k0 = (void*)gemm4b<0>;
  void* k1 = (void*)gemm4b<1>;
  hipFuncSetAttribute(k0, hipFuncAttributeMaxDynamicSharedMemorySize, 131072);
  hipFuncSetAttribute(k1, hipFuncAttributeMaxDynamicSharedMemorySize, 131072);

  router_kernel<<<CAP, 256, 0, stream>>>(x, rww, rwb, xb, rwout);

  dim3 tb(32,8);
  // W1 (E,H,I) -> W1^T per expert (I x H) bf16
  transpose_cvt<<<dim3(I_DIM/32, H_DIM/32, E_NUM), tb, 0, stream>>>(
      w1, wt, H_DIM, I_DIM, (long)H_DIM*I_DIM, (long)I_DIM*H_DIM);

  // GEMM1: inter[c, e*I+n] = bf16( relu( xb @ W1_e^T ) * rw[c,e] )
  // grid 512 = (4 mtiles x 16 ntiles) x 8 experts; K=1024 -> NH=32
  gemm4b<0><<<512, 512, 131072, stream>>>(
      xb, H_DIM, 0L,
      wt, H_DIM, (long)I_DIM*H_DIM,
      32, 64, rwout, inter, nullptr);

  // W2 flat (E*I x H) -> W2^T (H x E*I) bf16
  transpose_cvt<<<dim3(H_DIM/32, (E_NUM*I_DIM)/32, 1), tb, 0, stream>>>(
      w2, wt, E_NUM*I_DIM, H_DIM, 0L, 0L);

  // GEMM2: out[c,h] += inter[c,:] @ W2^T[h,:]; split-K z=16 slices of 2048 -> NH=64
  // grid 256 = (4 mtiles x 4 ntiles) x 16 z
  gemm4b<1><<<256, 512, 131072, stream>>>(
      inter, E_NUM*I_DIM, 2048L,
      wt,    E_NUM*I_DIM, 2048L,
      64, 16, nullptr, nullptr, out);
}